// Round 6
// baseline (469.536 us; speedup 1.0000x reference)
//
#include <hip/hip_runtime.h>

// Soft-DTW, B=64, L=1024, C=64, gamma=1.
// R2 skeleton: 16 row-bands of 64 rows per batch; wave = band; lane = row.
// One continuous skewed sweep per wave; 4 waves/block, 4 blocks/batch
// (256 blocks = 256 CUs, 1 wave/SIMD). Band handoff: LDS Hb in-block,
// global HX + agent flags across blocks.
// DP in EXPONENTIAL domain: cell stores V = 2^(-R) as (u, S), V = u*2^S,
// u in [0.5,1) f32 mantissa, S int32 scale. BIG == (u=0, S=-2^24).
//   V' = 2^(-D2) * (V_up + V_dg + V_lf)
//   Sm = max3(S); sum = sum_i ldexpf(u_i, S_i - Sm); un = sum * p
//   bit-frexp: un = mant * 2^ex, mant in [0.5,1);  u' = mant; S' = Sm - di + ex
// where D2 (base-2 units) is pre-split in gram as u32 = (di<<16)|f16(p=2^(di-D2)).
// ZERO transcendental ops and ZERO inline asm in the serial chain.
// Final cost R = -S - log2(u), reported * ln2.

typedef unsigned short ushort_t;
typedef __attribute__((ext_vector_type(8))) short short8;
typedef __attribute__((ext_vector_type(4))) float f32x4;
typedef __attribute__((ext_vector_type(4))) unsigned short ushort4v;

constexpr int B_ = 64, L_ = 1024, C_ = 64;
constexpr int DSTRW = 129;   // u32 row stride

#define BIGS (-(1 << 24))
#define INV_LN2 1.44269504088896340736f
#define LN2F 0.69314718055994530942f

static __device__ __forceinline__ ushort_t f2bf(float f) {
  unsigned u = __builtin_bit_cast(unsigned, f);
  unsigned r = (u + 0x7fffu + ((u >> 16) & 1u)) >> 16;
  return (ushort_t)r;
}
// lane i <- lane i-1; lane 0 <- old[0]   (wave_shr:1)
static __device__ __forceinline__ float dpp_shr1(float old, float src) {
  return __builtin_bit_cast(float, __builtin_amdgcn_update_dpp(
      __builtin_bit_cast(int, old), __builtin_bit_cast(int, src), 0x138, 0xF, 0xF, false));
}
static __device__ __forceinline__ int dpp_shr1_i(int old, int src) {
  return __builtin_amdgcn_update_dpp(old, src, 0x138, 0xF, 0xF, false);
}
// lane i <- lane i+1 (wave_shl:1, lane 63 keeps old)
static __device__ __forceinline__ float dpp_shl1(float v) {
  return __builtin_bit_cast(float, __builtin_amdgcn_update_dpp(
      __builtin_bit_cast(int, v), __builtin_bit_cast(int, v), 0x130, 0xF, 0xF, false));
}
static __device__ __forceinline__ int dpp_shl1_i(int v) {
  return __builtin_amdgcn_update_dpp(v, v, 0x130, 0xF, 0xF, false);
}
static __device__ __forceinline__ int imax3(int a, int b, int c) {
  int m = a > b ? a : b; return c > m ? c : m;
}

// Pass 1: bf16 conversion (RNE), norms scaled by 1/ln2 with +0.25 baked
// (so x2+y2 carries the +0.5 used for the round-half int split), zero flags.
__global__ __launch_bounds__(256) void prep_kernel(
    const float* __restrict__ x, const float* __restrict__ y,
    ushort_t* __restrict__ xb, ushort_t* __restrict__ yb,
    float* __restrict__ x2, float* __restrict__ y2, int* __restrict__ flagsG)
{
  if (blockIdx.x == 0 && threadIdx.x < 192) flagsG[threadIdx.x] = 0;
  const int lane = threadIdx.x & 63;
  const int sub = lane >> 4;
  const int cg  = lane & 15;
  const int wv = (blockIdx.x * blockDim.x + threadIdx.x) >> 6;
  const int nw = (gridDim.x * blockDim.x) >> 6;
  const int totalGroups = (2 * B_ * L_) >> 2;
  for (int g = wv; g < totalGroups; g += nw) {
    int r = g * 4 + sub;
    const float* src; ushort_t* dst; float* nrm;
    if (r < B_ * L_) { src = x; dst = xb; nrm = x2; }
    else             { r -= B_ * L_; src = y; dst = yb; nrm = y2; }
    const float4 v = *(const float4*)(src + (size_t)r * C_ + cg * 4);
    ushort4v p;
    p.x = f2bf(v.x); p.y = f2bf(v.y); p.z = f2bf(v.z); p.w = f2bf(v.w);
    *(ushort4v*)(dst + (size_t)r * C_ + cg * 4) = p;
    float s = v.x*v.x + v.y*v.y + v.z*v.z + v.w*v.w;
    s += __shfl_xor(s, 1); s += __shfl_xor(s, 2);
    s += __shfl_xor(s, 4); s += __shfl_xor(s, 8);
    if (cg == 0) nrm[r] = s * INV_LN2 + 0.25f;
  }
}

// One 64-step chunk, exp-domain. HDST: 0 = LDS Hb, 1 = global HX, 2 = none.
template<int HDST, bool FIRST>
static __device__ __forceinline__ void dp_chunk(
    const int t, const int lane,
    float& cur_u, int& cur_S, float& dgp_u, int& dgp_S,
    float hv_u, int hv_S, const float zu, const int zS,
    const unsigned* __restrict__ DtLane,
    float2* __restrict__ HbDst, float2* __restrict__ HXB)
{
  const unsigned* pw = DtLane + ((t & 1) << 6);
  const int cb = (t << 6) - 63;          // lane-63 col at local step u is cb+u
  unsigned d0=pw[0],d1=pw[1],d2=pw[2],d3=pw[3],d4=pw[4],d5=pw[5],d6=pw[6],d7=pw[7];

  auto step = [&](unsigned dw, int u) {
    float up_u = dpp_shr1(hv_u, cur_u);  // lane0 <- external top value
    int   up_S = dpp_shr1_i(hv_S, cur_S);
    hv_u = dpp_shl1(hv_u);
    hv_S = dpp_shl1_i(hv_S);
    float p = (float)__builtin_bit_cast(_Float16, (unsigned short)(dw & 0xffffu));
    int di = (int)(dw >> 16);            // int part of D2, >= 0
    float dg_u = dgp_u, lf_u = cur_u;
    int   dg_S = dgp_S, lf_S = cur_S;
    if constexpr (FIRST) {
      const bool a0 = (u == lane);       // col == 0: left boundary
      dg_u = a0 ? zu : dg_u;  dg_S = a0 ? zS : dg_S;
      lf_u = a0 ? 0.f : lf_u; lf_S = a0 ? BIGS : lf_S;
    }
    int Sm = imax3(up_S, dg_S, lf_S);
    float sa = ldexpf(up_u, up_S - Sm);
    float sb = ldexpf(dg_u, dg_S - Sm);
    float sc = ldexpf(lf_u, lf_S - Sm);
    float un = ((sa + sb) + sc) * p;     // = V' * 2^(di - Sm); in [0.35, 4.25] when live
    int ub = __float_as_int(un);
    int ex = ((ub >> 23) & 0xff) - 126;  // un==0 -> pseudo-BIG, flushed downstream
    float mant = __int_as_float((ub & 0x007fffff) | 0x3f000000);
    int Sn = Sm - di + ex;               // V' = mant * 2^Sn
    dgp_u = up_u; dgp_S = up_S;
    const bool wr = FIRST ? (u >= lane) : true;
    if (wr) { cur_u = mant; cur_S = Sn; }
    if constexpr (!FIRST && HDST != 2) {
      if (lane == 63) {
        float2 pr; pr.x = mant; pr.y = __int_as_float(Sn);
        if constexpr (HDST == 0) HbDst[cb + u] = pr;
        else                     HXB[cb + u] = pr;
      }
    }
  };

  #pragma unroll 1
  for (int g = 0; g < 8; ++g) {
    unsigned n0=0,n1=0,n2=0,n3=0,n4=0,n5=0,n6=0,n7=0;
    if (g < 7) {
      const unsigned* np = pw + ((g + 1) << 3);
      n0=np[0]; n1=np[1]; n2=np[2]; n3=np[3]; n4=np[4]; n5=np[5]; n6=np[6]; n7=np[7];
    }
    const int u0 = g << 3;
    step(d0, u0+0); step(d1, u0+1); step(d2, u0+2); step(d3, u0+3);
    step(d4, u0+4); step(d5, u0+5); step(d6, u0+6); step(d7, u0+7);
    d0=n0; d1=n1; d2=n2; d3=n3; d4=n4; d5=n5; d6=n6; d7=n7;
  }
  if constexpr (FIRST && HDST != 2) {
    // chunk 0: lane 63's only valid col is 0 (reached at u=63)
    if (lane == 63) {
      float2 pr; pr.x = cur_u; pr.y = __int_as_float(cur_S);
      if constexpr (HDST == 0) HbDst[0] = pr; else HXB[0] = pr;
    }
  }
}

// Tail: 63 skew-drain steps, c = 1024 + u - lane, valid iff u < lane.
template<int HDST>
static __device__ __forceinline__ void dp_tail(
    const int lane, float& cur_u, int& cur_S, float& dgp_u, int& dgp_S,
    const unsigned* __restrict__ DtLane,
    float2* __restrict__ HbDst, float2* __restrict__ HXB)
{
  const unsigned* pw = DtLane;           // chunk 16 -> slots 0..63
  #pragma unroll 1
  for (int g = 0; g < 8; ++g) {
    unsigned w0=pw[g*8],w1=pw[g*8+1],w2=pw[g*8+2],w3=pw[g*8+3],
             w4=pw[g*8+4],w5=pw[g*8+5],w6=pw[g*8+6],w7=pw[g*8+7];
    #pragma unroll
    for (int k = 0; k < 8; ++k) {
      const int u = g * 8 + k;
      unsigned dw = (k==0)?w0:(k==1)?w1:(k==2)?w2:(k==3)?w3:(k==4)?w4:(k==5)?w5:(k==6)?w6:w7;
      float up_u = dpp_shr1(0.f, cur_u);
      int   up_S = dpp_shr1_i(BIGS, cur_S);
      float p = (float)__builtin_bit_cast(_Float16, (unsigned short)(dw & 0xffffu));
      int di = (int)(dw >> 16);
      int Sm = imax3(up_S, dgp_S, cur_S);
      float sa = ldexpf(up_u, up_S - Sm);
      float sb = ldexpf(dgp_u, dgp_S - Sm);
      float sc = ldexpf(cur_u, cur_S - Sm);
      float un = ((sa + sb) + sc) * p;
      int ub = __float_as_int(un);
      int ex = ((ub >> 23) & 0xff) - 126;
      float mant = __int_as_float((ub & 0x007fffff) | 0x3f000000);
      int Sn = Sm - di + ex;
      dgp_u = up_u; dgp_S = up_S;
      if (u < lane) {
        cur_u = mant; cur_S = Sn;
        if (lane == 63) {
          float2 pr; pr.x = mant; pr.y = __int_as_float(Sn);
          if constexpr (HDST == 0) HbDst[961 + u] = pr;
          else if constexpr (HDST == 1) HXB[961 + u] = pr;
        }
      }
    }
  }
}

static __device__ __forceinline__ void spin_lds(int* f, int v) {
  int k = 0;
  while (__hip_atomic_load(f, __ATOMIC_ACQUIRE, __HIP_MEMORY_SCOPE_WORKGROUP) < v) {
    __builtin_amdgcn_s_sleep(1);
    if (++k > (1 << 26)) break;
  }
}
static __device__ __forceinline__ void spin_glb(int* f, int v) {
  int k = 0;
  while (__hip_atomic_load(f, __ATOMIC_ACQUIRE, __HIP_MEMORY_SCOPE_AGENT) < v) {
    __builtin_amdgcn_s_sleep(2);
    if (++k > (1 << 26)) break;
  }
}

// HSRC: 0 = BIG top (band 0), 1 = LDS Hb, 2 = global HX.
// HDST: 0 = LDS Hb, 1 = global HX, 2 = none (band 15).
template<int HSRC, int HDST>
static __device__ __forceinline__ void run_band(
    const ushort_t* __restrict__ xbB, const ushort_t* __restrict__ ybB,
    const float* __restrict__ x2B, const float* __restrict__ y2B,
    const float2* __restrict__ HXin, float2* __restrict__ HXout,
    int* __restrict__ fGin, int* __restrict__ fGout,
    unsigned* __restrict__ Dtw, const float2* __restrict__ HbSrc,
    float2* __restrict__ HbDst, int* __restrict__ cin, int* __restrict__ cout,
    const int lane, const int W, float* __restrict__ outp)
{
  const int m = lane & 15, q = lane >> 4;
  const int i0 = W * 64;

  short8 af[4][2];
  #pragma unroll
  for (int mt = 0; mt < 4; ++mt)
    #pragma unroll
    for (int ks = 0; ks < 2; ++ks)
      af[mt][ks] = *(const short8*)(xbB + (size_t)(i0 + mt * 16 + m) * C_ + ks * 32 + q * 8);
  f32x4 x2q[4];
  #pragma unroll
  for (int mt = 0; mt < 4; ++mt) x2q[mt] = *(const f32x4*)(x2B + i0 + mt * 16 + q * 4);

  short8 bfr0[4], bfr1[4];
  f32x4 y2r = {0.f, 0.f, 0.f, 0.f};
  auto load_bfr = [&](int tc) {
    const ushort_t* yb0 = ybB + (size_t)tc * 64 * C_;
    #pragma unroll
    for (int nt = 0; nt < 4; ++nt) {
      bfr0[nt] = *(const short8*)(yb0 + (size_t)(nt * 16 + m) * C_ + q * 8);
      bfr1[nt] = *(const short8*)(yb0 + (size_t)(nt * 16 + m) * C_ + 32 + q * 8);
      y2r[nt] = y2B[tc * 64 + nt * 16 + m];
    }
  };
  // Gram tile tc -> skewed LDS u32 cells: row r, slot (col+r)&127,
  // cell = (di<<16) | f16(p),  p = 2^(di - D2) in [0.707, 1.415)
  auto gram = [&](int tc) {
    const int cb = tc * 64;
    #pragma unroll
    for (int mt = 0; mt < 4; ++mt) {
      const int r0 = mt * 16 + q * 4;
      #pragma unroll
      for (int nt = 0; nt < 4; ++nt) {
        f32x4 acc = {0.f, 0.f, 0.f, 0.f};
        acc = __builtin_amdgcn_mfma_f32_16x16x32_bf16(af[mt][0], bfr0[nt], acc, 0, 0, 0);
        acc = __builtin_amdgcn_mfma_f32_16x16x32_bf16(af[mt][1], bfr1[nt], acc, 0, 0, 0);
        const float y2v = y2r[nt];
        const int cs = cb + nt * 16 + m + r0;
        #pragma unroll
        for (int reg = 0; reg < 4; ++reg) {
          float d = fmaf(acc[reg], -2.f * INV_LN2, x2q[mt][reg] + y2v); // D2 + 0.5
          d = fmaxf(d, 0.5f);                               // guard: di >= 0
          int di = (int)d;                                  // trunc = round(D2)
          float pe = (float)di + 0.5f - d;                  // in (-0.5, 0.5]
          float p = __builtin_amdgcn_exp2f(pe);
          unsigned short hb = __builtin_bit_cast(unsigned short, (_Float16)p);
          Dtw[(r0 + reg) * DSTRW + ((cs + reg) & 127)] = ((unsigned)di << 16) | (unsigned)hb;
        }
      }
    }
  };
  auto signal = [&](int v) {
    if constexpr (HDST == 0) {
      if (lane == 0) __hip_atomic_store(cout, v, __ATOMIC_RELEASE, __HIP_MEMORY_SCOPE_WORKGROUP);
    } else if constexpr (HDST == 1) {
      if (lane == 0) __hip_atomic_store(fGout, v, __ATOMIC_RELEASE, __HIP_MEMORY_SCOPE_AGENT);
    }
  };

  float cur_u = 0.f, dgp_u = 0.f;
  int cur_S = BIGS, dgp_S = BIGS;
  const float zu = (W == 0 && lane == 0) ? 1.0f : 0.f;    // V(R=0)=1 at origin
  const int   zS = (W == 0 && lane == 0) ? 0 : BIGS;
  const unsigned* DtLane = Dtw + lane * DSTRW;

  load_bfr(0);
  gram(0);

  #pragma unroll 1
  for (int t = 0; t < 16; ++t) {
    if (t < 15) load_bfr(t + 1);
    float hv_u; int hv_S;
    if constexpr (HSRC == 0) {
      hv_u = 0.f; hv_S = BIGS;
    } else if constexpr (HSRC == 1) {
      spin_lds(cin, t + 1);
      float2 pr = HbSrc[(t << 6) + lane];
      hv_u = pr.x; hv_S = __float_as_int(pr.y);
    } else {
      spin_glb(fGin, t + 1);
      float2 pr = HXin[(t << 6) + lane];
      hv_u = pr.x; hv_S = __float_as_int(pr.y);
    }
    if (t == 0)
      dp_chunk<HDST, true >(0, lane, cur_u, cur_S, dgp_u, dgp_S, hv_u, hv_S, zu, zS, DtLane, HbDst, HXout);
    else
      dp_chunk<HDST, false>(t, lane, cur_u, cur_S, dgp_u, dgp_S, hv_u, hv_S, zu, zS, DtLane, HbDst, HXout);
    signal(t);
    if (t < 15) gram(t + 1);
  }
  dp_tail<HDST>(lane, cur_u, cur_S, dgp_u, dgp_S, DtLane, HbDst, HXout);
  signal(16);
  if (W == 15 && lane == 63) {
    float uu = fmaxf(cur_u, 1e-30f);
    *outp = (-(float)cur_S - __builtin_amdgcn_logf(uu)) * LN2F;  // R = -S - log2(u)
  }
}

__global__ __launch_bounds__(256) void sdtw_kernel(
    const ushort_t* __restrict__ xb, const ushort_t* __restrict__ yb,
    const float* __restrict__ x2g, const float* __restrict__ y2g,
    float2* __restrict__ HXg, int* __restrict__ flagsG,
    float* __restrict__ out)
{
  // LDS: Dt 4*64*129*4 = 132096 ; Hb 3*1024*8 = 24576 ; cflag 16 => 156688 B
  __shared__ unsigned Dt[4][64 * DSTRW];
  __shared__ float2 Hb[3][1024];
  __shared__ int cflag[4];

  const int b = blockIdx.x & 63;       // blocks b, b+64, b+128, b+192: same XCD slot
  const int sub = blockIdx.x >> 6;     // 0..3 -> bands sub*4 .. sub*4+3
  const int w = threadIdx.x >> 6;
  const int lane = threadIdx.x & 63;
  const int W = sub * 4 + w;

  if (threadIdx.x < 4) cflag[threadIdx.x] = 0;
  __syncthreads();                     // only barrier in the kernel

  const ushort_t* xbB = xb + (size_t)b * L_ * C_;
  const ushort_t* ybB = yb + (size_t)b * L_ * C_;
  const float* x2B = x2g + b * L_;
  const float* y2B = y2g + b * L_;
  // boundary buffers: HXg[b][bnd][1024], bnd = 0,1,2 after bands 3,7,11
  const float2* HXin = HXg + ((size_t)b * 3 + (sub > 0 ? sub - 1 : 0)) * L_;
  float2* HXout      = HXg + ((size_t)b * 3 + (sub < 3 ? sub : 2)) * L_;
  int* fGin  = flagsG + b * 3 + (sub > 0 ? sub - 1 : 0);
  int* fGout = flagsG + b * 3 + (sub < 3 ? sub : 2);
  unsigned* Dtw = &Dt[w][0];
  const float2* HbSrc = (w > 0) ? &Hb[w - 1][0] : &Hb[0][0];
  float2* HbDst = (w < 3) ? &Hb[w][0] : &Hb[0][0];
  int* cin  = (w > 0) ? &cflag[w - 1] : &cflag[0];
  int* cout = (w < 3) ? &cflag[w] : &cflag[3];
  float* outp = out + b;

  if (sub == 0) {
    if (w == 0)      run_band<0, 0>(xbB, ybB, x2B, y2B, HXin, HXout, fGin, fGout, Dtw, HbSrc, HbDst, cin, cout, lane, W, outp);
    else if (w < 3)  run_band<1, 0>(xbB, ybB, x2B, y2B, HXin, HXout, fGin, fGout, Dtw, HbSrc, HbDst, cin, cout, lane, W, outp);
    else             run_band<1, 1>(xbB, ybB, x2B, y2B, HXin, HXout, fGin, fGout, Dtw, HbSrc, HbDst, cin, cout, lane, W, outp);
  } else if (sub < 3) {
    if (w == 0)      run_band<2, 0>(xbB, ybB, x2B, y2B, HXin, HXout, fGin, fGout, Dtw, HbSrc, HbDst, cin, cout, lane, W, outp);
    else if (w < 3)  run_band<1, 0>(xbB, ybB, x2B, y2B, HXin, HXout, fGin, fGout, Dtw, HbSrc, HbDst, cin, cout, lane, W, outp);
    else             run_band<1, 1>(xbB, ybB, x2B, y2B, HXin, HXout, fGin, fGout, Dtw, HbSrc, HbDst, cin, cout, lane, W, outp);
  } else {
    if (w == 0)      run_band<2, 0>(xbB, ybB, x2B, y2B, HXin, HXout, fGin, fGout, Dtw, HbSrc, HbDst, cin, cout, lane, W, outp);
    else if (w < 3)  run_band<1, 0>(xbB, ybB, x2B, y2B, HXin, HXout, fGin, fGout, Dtw, HbSrc, HbDst, cin, cout, lane, W, outp);
    else             run_band<1, 2>(xbB, ybB, x2B, y2B, HXin, HXout, fGin, fGout, Dtw, HbSrc, HbDst, cin, cout, lane, W, outp);
  }
}

extern "C" void kernel_launch(void* const* d_in, const int* in_sizes, int n_in,
                              void* d_out, int out_size, void* d_ws, size_t ws_size,
                              hipStream_t stream) {
  const float* x = (const float*)d_in[0];
  const float* y = (const float*)d_in[1];
  float* out = (float*)d_out;

  // ws: xb 8MB | yb 8MB | x2 256KB | y2 256KB | HX (float2) 1.5MB | flagsG 768B
  char* ws = (char*)d_ws;
  const size_t XB = (size_t)B_ * L_ * C_ * 2;
  const size_t NB = (size_t)B_ * L_ * 4;
  ushort_t* xb = (ushort_t*)ws;
  ushort_t* yb = (ushort_t*)(ws + XB);
  float* x2 = (float*)(ws + 2 * XB);
  float* y2 = (float*)(ws + 2 * XB + NB);
  float2* HX = (float2*)(ws + 2 * XB + 2 * NB);
  int* flagsG = (int*)(ws + 2 * XB + 2 * NB + (size_t)B_ * 3 * L_ * 8);

  prep_kernel<<<512, 256, 0, stream>>>(x, y, xb, yb, x2, y2, flagsG);
  sdtw_kernel<<<256, 256, 0, stream>>>(xb, yb, x2, y2, HX, flagsG, out);
}

// Round 7
// 383.612 us; speedup vs baseline: 1.2240x; 1.2240x over previous
//
#include <hip/hip_runtime.h>

// Soft-DTW, B=64, L=1024, C=64, gamma=1.
// 16 row-bands of 64 rows per batch; wave = band; lane = row.
// One continuous skewed sweep per wave. NEW vs R2: 8 waves/block (512 thr),
// 2 blocks/batch (128 blocks, 1/CU) -> waves w and w+4 share a SIMD and are
// 8 chunks apart in the pipeline: their dependent chains interleave, lifting
// SIMD duty from ~48% to ~90%+. Band handoff: LDS Hb + flags in-block (7
// boundaries); ONE global HX + agent flag per batch across the two blocks.
// DP in base-2 log domain (D pre-scaled by 1/ln2), softmin via med3 identity:
// e = 1 + 2^(mn-med) + 2^(mn-max)  (one exp2 fewer per step; trans pipe is
// shared by 2 waves/SIMD). No inline asm in the DP chain (R4/R5 lesson).

typedef unsigned short ushort_t;
typedef __attribute__((ext_vector_type(8))) short short8;
typedef __attribute__((ext_vector_type(4))) float f32x4;
typedef __attribute__((ext_vector_type(4))) unsigned short ushort4v;

constexpr int B_ = 64, L_ = 1024, C_ = 64;
constexpr int DSTR = 130;   // u16 row stride (65 dwords): bank = (r + const)&31, 2-way

#define BIGV 1e10f
#define INV_LN2 1.44269504088896340736f
#define LN2F 0.69314718055994530942f

static __device__ __forceinline__ ushort_t f2bf(float f) {
  unsigned u = __builtin_bit_cast(unsigned, f);
  unsigned r = (u + 0x7fffu + ((u >> 16) & 1u)) >> 16;
  return (ushort_t)r;
}
static __device__ __forceinline__ unsigned cvt_pk_bf16(float lo, float hi) {
  unsigned r; asm("v_cvt_pk_bf16_f32 %0, %1, %2" : "=v"(r) : "v"(lo), "v"(hi)); return r;
}
// lane i <- lane i-1; lane 0 <- old[0]   (wave_shr:1)
static __device__ __forceinline__ float dpp_shr1(float old, float src) {
  return __builtin_bit_cast(float, __builtin_amdgcn_update_dpp(
      __builtin_bit_cast(int, old), __builtin_bit_cast(int, src), 0x138, 0xF, 0xF, false));
}
// lane i <- lane i+1 (wave_shl:1, lane 63 keeps old)
static __device__ __forceinline__ float dpp_shl1(float v) {
  return __builtin_bit_cast(float, __builtin_amdgcn_update_dpp(
      __builtin_bit_cast(int, v), __builtin_bit_cast(int, v), 0x130, 0xF, 0xF, false));
}

// Pass 1: bf16 conversion (RNE), squared norms pre-scaled by 1/ln2, zero flags.
__global__ __launch_bounds__(256) void prep_kernel(
    const float* __restrict__ x, const float* __restrict__ y,
    ushort_t* __restrict__ xb, ushort_t* __restrict__ yb,
    float* __restrict__ x2, float* __restrict__ y2, int* __restrict__ flagsG)
{
  if (blockIdx.x == 0 && threadIdx.x < 64) flagsG[threadIdx.x] = 0;
  const int lane = threadIdx.x & 63;
  const int sub = lane >> 4;
  const int cg  = lane & 15;
  const int wv = (blockIdx.x * blockDim.x + threadIdx.x) >> 6;
  const int nw = (gridDim.x * blockDim.x) >> 6;
  const int totalGroups = (2 * B_ * L_) >> 2;
  for (int g = wv; g < totalGroups; g += nw) {
    int r = g * 4 + sub;
    const float* src; ushort_t* dst; float* nrm;
    if (r < B_ * L_) { src = x; dst = xb; nrm = x2; }
    else             { r -= B_ * L_; src = y; dst = yb; nrm = y2; }
    const float4 v = *(const float4*)(src + (size_t)r * C_ + cg * 4);
    ushort4v p;
    p.x = f2bf(v.x); p.y = f2bf(v.y); p.z = f2bf(v.z); p.w = f2bf(v.w);
    *(ushort4v*)(dst + (size_t)r * C_ + cg * 4) = p;
    float s = v.x*v.x + v.y*v.y + v.z*v.z + v.w*v.w;
    s += __shfl_xor(s, 1); s += __shfl_xor(s, 2);
    s += __shfl_xor(s, 4); s += __shfl_xor(s, 8);
    if (cg == 0) nrm[r] = s * INV_LN2;
  }
}

// One 64-step chunk. HDST: 0 = LDS Hb, 1 = global HX, 2 = none.
// FIRST: chunk 0 (left-boundary gating).
template<int HDST, bool FIRST>
static __device__ __forceinline__ void dp_chunk(
    const int t, const int lane, float& cur, float& dgp, float hvv,
    const float zsel, const ushort_t* __restrict__ DtLane,
    float* __restrict__ HbDst, float* __restrict__ HXB)
{
  const unsigned* pw = (const unsigned*)(DtLane + ((t << 6) & 127));
  const int cb = (t << 6) - 63;        // lane-63 col for local step u is cb+u
  unsigned a0 = pw[0], a1 = pw[1], b0 = pw[2], b1 = pw[3];

  auto step = [&](unsigned dw, int k, int u) -> float {
    float dv = __builtin_bit_cast(float, (k & 1) ? (dw & 0xffff0000u) : (dw << 16));
    float up = dpp_shr1(hvv, cur);     // lane0 <- hvv[0] = top row value
    float dg = dgp, lf = cur;
    if constexpr (FIRST) {
      bool at0 = (u == lane);          // c == 0: left boundary
      dg = at0 ? zsel : dg;
      lf = at0 ? BIGV : lf;
    }
    float mn = fminf(fminf(up, dg), lf);
    float mx = fmaxf(fmaxf(up, dg), lf);
    float md = fmaxf(fminf(up, dg), fminf(fmaxf(up, dg), lf));
    float e = 1.0f + (__builtin_amdgcn_exp2f(mn - md) + __builtin_amdgcn_exp2f(mn - mx));
    float nv = (dv + mn) - __builtin_amdgcn_logf(e);   // v_log_f32 = log2
    dgp = up;
    hvv = dpp_shl1(hvv);               // advance top-row value toward lane 0
    if constexpr (FIRST) { if (u >= lane) cur = nv; }
    else cur = nv;
    return nv;
  };
  auto flush4 = [&](int c0, float v0, float v1, float v2, float v3) {
    if constexpr (HDST == 0) {
      if (lane == 63) { HbDst[c0] = v0; HbDst[c0+1] = v1; HbDst[c0+2] = v2; HbDst[c0+3] = v3; }
    } else if constexpr (HDST == 1) {
      if (lane == 63) { HXB[c0] = v0; HXB[c0+1] = v1; HXB[c0+2] = v2; HXB[c0+3] = v3; }
    }
  };

  #pragma unroll 1
  for (int g = 0; g < 8; ++g) {
    const int u0 = g * 8;
    unsigned n0 = 0, n1 = 0, n2 = 0, n3 = 0;
    if (g < 7) {
      n0 = pw[u0/2 + 4]; n1 = pw[u0/2 + 5]; n2 = pw[u0/2 + 6]; n3 = pw[u0/2 + 7];
    }
    float v0 = step(a0, 0, u0 + 0);
    float v1 = step(a0, 1, u0 + 1);
    float v2 = step(a1, 0, u0 + 2);
    float v3 = step(a1, 1, u0 + 3);
    if constexpr (!FIRST) flush4(cb + u0, v0, v1, v2, v3);
    float v4 = step(b0, 0, u0 + 4);
    float v5 = step(b0, 1, u0 + 5);
    float v6 = step(b1, 0, u0 + 6);
    float v7 = step(b1, 1, u0 + 7);
    if constexpr (!FIRST) flush4(cb + u0 + 4, v4, v5, v6, v7);
    a0 = n0; a1 = n1; b0 = n2; b1 = n3;
    (void)v0; (void)v1; (void)v2; (void)v3; (void)v4; (void)v5; (void)v6; (void)v7;
  }
  if constexpr (FIRST) {
    // chunk 0: lane 63's only valid col is 0 (reached at u=63, value in cur)
    if constexpr (HDST == 0) { if (lane == 63) HbDst[0] = cur; }
    else if constexpr (HDST == 1) { if (lane == 63) HXB[0] = cur; }
  }
}

// Tail: 63 skew-drain steps, c = 1024 + u - lane, valid iff u < lane.
template<int HDST>
static __device__ __forceinline__ void dp_tail(
    const int lane, float& cur, float& dgp,
    const ushort_t* __restrict__ DtLane,
    float* __restrict__ HbDst, float* __restrict__ HXB)
{
  const unsigned* pw = (const unsigned*)(DtLane);   // slots 0..63 ((1024)&127==0)
  #pragma unroll 1
  for (int g = 0; g < 8; ++g) {
    unsigned w0 = pw[g*4], w1 = pw[g*4+1], w2 = pw[g*4+2], w3 = pw[g*4+3];
    #pragma unroll
    for (int k = 0; k < 8; ++k) {
      const int u = g * 8 + k;
      unsigned dw = (k < 2) ? w0 : (k < 4) ? w1 : (k < 6) ? w2 : w3;
      float dv = __builtin_bit_cast(float, (k & 1) ? (dw & 0xffff0000u) : (dw << 16));
      float up = dpp_shr1(BIGV, cur);
      float dg = dgp, lf = cur;
      float mn = fminf(fminf(up, dg), lf);
      float mx = fmaxf(fmaxf(up, dg), lf);
      float md = fmaxf(fminf(up, dg), fminf(fmaxf(up, dg), lf));
      float e = 1.0f + (__builtin_amdgcn_exp2f(mn - md) + __builtin_amdgcn_exp2f(mn - mx));
      float nv = (dv + mn) - __builtin_amdgcn_logf(e);
      dgp = up;
      if (u < lane) {
        cur = nv;
        if (lane == 63) {
          if constexpr (HDST == 0) HbDst[961 + u] = nv;
          else if constexpr (HDST == 1) HXB[961 + u] = nv;
        }
      }
    }
  }
}

static __device__ __forceinline__ void spin_lds(int* f, int v) {
  int k = 0;
  while (__hip_atomic_load(f, __ATOMIC_ACQUIRE, __HIP_MEMORY_SCOPE_WORKGROUP) < v) {
    __builtin_amdgcn_s_sleep(1);
    if (++k > (1 << 26)) break;
  }
}
static __device__ __forceinline__ void spin_glb(int* f, int v) {
  int k = 0;
  while (__hip_atomic_load(f, __ATOMIC_ACQUIRE, __HIP_MEMORY_SCOPE_AGENT) < v) {
    __builtin_amdgcn_s_sleep(2);
    if (++k > (1 << 26)) break;
  }
}

// HSRC: 0 = BIG top boundary (band 0), 1 = LDS Hb, 2 = global HX.
// HDST: 0 = LDS Hb, 1 = global HX, 2 = none (band 15).
template<int HSRC, int HDST>
static __device__ __forceinline__ void run_band(
    const ushort_t* __restrict__ xbB, const ushort_t* __restrict__ ybB,
    const float* __restrict__ x2B, const float* __restrict__ y2B,
    const float* __restrict__ HXin, float* __restrict__ HXout,
    int* __restrict__ fGin, int* __restrict__ fGout,
    ushort_t* __restrict__ Dtw, const float* __restrict__ HbSrc,
    float* __restrict__ HbDst, int* __restrict__ cin, int* __restrict__ cout,
    const int lane, const int W, float* __restrict__ outp)
{
  const int m = lane & 15, q = lane >> 4;
  const int i0 = W * 64;

  short8 af[4][2];
  #pragma unroll
  for (int mt = 0; mt < 4; ++mt)
    #pragma unroll
    for (int ks = 0; ks < 2; ++ks)
      af[mt][ks] = *(const short8*)(xbB + (size_t)(i0 + mt * 16 + m) * C_ + ks * 32 + q * 8);
  f32x4 x2q[4];
  #pragma unroll
  for (int mt = 0; mt < 4; ++mt) x2q[mt] = *(const f32x4*)(x2B + i0 + mt * 16 + q * 4);

  short8 bfr0[4], bfr1[4];
  auto load_bfr = [&](int tc) {
    const ushort_t* yb0 = ybB + (size_t)tc * 64 * C_;
    #pragma unroll
    for (int nt = 0; nt < 4; ++nt) {
      bfr0[nt] = *(const short8*)(yb0 + (size_t)(nt * 16 + m) * C_ + q * 8);
      bfr1[nt] = *(const short8*)(yb0 + (size_t)(nt * 16 + m) * C_ + 32 + q * 8);
    }
  };
  // Gram tile -> skewed LDS: D[r][c] at row r, slot (c+r)&127 (base-2 scaled bf16)
  auto gram = [&](int tc) {
    const int cb = tc * 64;
    const float* y2j = y2B + cb;
    #pragma unroll
    for (int mt = 0; mt < 4; ++mt) {
      const int r0 = mt * 16 + q * 4;
      #pragma unroll
      for (int nt = 0; nt < 4; ++nt) {
        f32x4 acc = {0.f, 0.f, 0.f, 0.f};
        acc = __builtin_amdgcn_mfma_f32_16x16x32_bf16(af[mt][0], bfr0[nt], acc, 0, 0, 0);
        acc = __builtin_amdgcn_mfma_f32_16x16x32_bf16(af[mt][1], bfr1[nt], acc, 0, 0, 0);
        float y2v = y2j[nt * 16 + m];
        float d0 = fmaf(acc[0], -2.f * INV_LN2, x2q[mt][0] + y2v);
        float d1 = fmaf(acc[1], -2.f * INV_LN2, x2q[mt][1] + y2v);
        float d2 = fmaf(acc[2], -2.f * INV_LN2, x2q[mt][2] + y2v);
        float d3 = fmaf(acc[3], -2.f * INV_LN2, x2q[mt][3] + y2v);
        unsigned p01 = cvt_pk_bf16(d0, d1);
        unsigned p23 = cvt_pk_bf16(d2, d3);
        const int cs = cb + nt * 16 + m + r0;      // col + row for reg 0
        ushort_t* base = Dtw + r0 * DSTR;
        base[             ( cs      & 127)] = (ushort_t)p01;
        base[    DSTR  +  ((cs + 1) & 127)] = (ushort_t)(p01 >> 16);
        base[2 * DSTR  +  ((cs + 2) & 127)] = (ushort_t)p23;
        base[3 * DSTR  +  ((cs + 3) & 127)] = (ushort_t)(p23 >> 16);
      }
    }
  };
  auto signal = [&](int v) {
    if constexpr (HDST == 0) {
      if (lane == 0) __hip_atomic_store(cout, v, __ATOMIC_RELEASE, __HIP_MEMORY_SCOPE_WORKGROUP);
    } else if constexpr (HDST == 1) {
      if (lane == 0) __hip_atomic_store(fGout, v, __ATOMIC_RELEASE, __HIP_MEMORY_SCOPE_AGENT);
    }
  };

  float cur = 0.f, dgp = BIGV;
  const float zsel = (W == 0 && lane == 0) ? 0.0f : BIGV;  // R[-1][-1]=0 at origin
  const ushort_t* DtLane = Dtw + lane * DSTR;

  load_bfr(0);
  gram(0);

  #pragma unroll 1
  for (int t = 0; t < 16; ++t) {
    if (t < 15) load_bfr(t + 1);
    float hvv;
    if constexpr (HSRC == 0) {
      hvv = BIGV;
    } else if constexpr (HSRC == 1) {
      spin_lds(cin, t + 1);
      hvv = HbSrc[(t << 6) + lane];
    } else {
      spin_glb(fGin, t + 1);
      hvv = HXin[(t << 6) + lane];
    }
    if (t == 0) dp_chunk<HDST, true >(0, lane, cur, dgp, hvv, zsel, DtLane, HbDst, HXout);
    else        dp_chunk<HDST, false>(t, lane, cur, dgp, hvv, zsel, DtLane, HbDst, HXout);
    signal(t);
    if (t < 15) gram(t + 1);
  }
  dp_tail<HDST>(lane, cur, dgp, DtLane, HbDst, HXout);
  signal(16);
  if (W == 15 && lane == 63) *outp = cur * LN2F;
}

__global__ __launch_bounds__(512) void sdtw_kernel(
    const ushort_t* __restrict__ xb, const ushort_t* __restrict__ yb,
    const float* __restrict__ x2g, const float* __restrict__ y2g,
    float* __restrict__ HXg, int* __restrict__ flagsG,
    float* __restrict__ out)
{
  // LDS: Dt 8*64*130*2 = 133120 ; Hb 7*1024*4 = 28672 ; cflag 32 => 161824 B
  // (1 block/CU, 8 waves = 2/SIMD; waves w and w+4 share a SIMD, 8 chunks apart)
  __shared__ ushort_t Dt[8][64 * DSTR];
  __shared__ float Hb[7][1024];
  __shared__ int cflag[8];

  const int b = blockIdx.x & 63;       // blocks b and b+64: same XCD slot (128 % 8)
  const int sub = blockIdx.x >> 6;     // 0: bands 0-7, 1: bands 8-15
  const int w = threadIdx.x >> 6;
  const int lane = threadIdx.x & 63;
  const int W = sub * 8 + w;

  if (threadIdx.x < 8) cflag[threadIdx.x] = 0;
  __syncthreads();                     // only barrier in the kernel

  const ushort_t* xbB = xb + (size_t)b * L_ * C_;
  const ushort_t* ybB = yb + (size_t)b * L_ * C_;
  const float* x2B = x2g + b * L_;
  const float* y2B = y2g + b * L_;
  const float* HXin = HXg + (size_t)b * L_;   // single boundary: band 7 -> 8
  float* HXout     = HXg + (size_t)b * L_;
  int* fGin  = flagsG + b;
  int* fGout = flagsG + b;
  ushort_t* Dtw = &Dt[w][0];
  const float* HbSrc = (w > 0) ? &Hb[w - 1][0] : &Hb[0][0];
  float* HbDst = (w < 7) ? &Hb[w][0] : &Hb[0][0];
  int* cin  = (w > 0) ? &cflag[w - 1] : &cflag[0];
  int* cout = (w < 7) ? &cflag[w] : &cflag[7];
  float* outp = out + b;

  if (sub == 0) {
    if (w == 0)
      run_band<0, 0>(xbB, ybB, x2B, y2B, HXin, HXout, fGin, fGout, Dtw, HbSrc, HbDst, cin, cout, lane, W, outp);
    else if (w < 7)
      run_band<1, 0>(xbB, ybB, x2B, y2B, HXin, HXout, fGin, fGout, Dtw, HbSrc, HbDst, cin, cout, lane, W, outp);
    else
      run_band<1, 1>(xbB, ybB, x2B, y2B, HXin, HXout, fGin, fGout, Dtw, HbSrc, HbDst, cin, cout, lane, W, outp);
  } else {
    if (w == 0)
      run_band<2, 0>(xbB, ybB, x2B, y2B, HXin, HXout, fGin, fGout, Dtw, HbSrc, HbDst, cin, cout, lane, W, outp);
    else if (w < 7)
      run_band<1, 0>(xbB, ybB, x2B, y2B, HXin, HXout, fGin, fGout, Dtw, HbSrc, HbDst, cin, cout, lane, W, outp);
    else
      run_band<1, 2>(xbB, ybB, x2B, y2B, HXin, HXout, fGin, fGout, Dtw, HbSrc, HbDst, cin, cout, lane, W, outp);
  }
}

extern "C" void kernel_launch(void* const* d_in, const int* in_sizes, int n_in,
                              void* d_out, int out_size, void* d_ws, size_t ws_size,
                              hipStream_t stream) {
  const float* x = (const float*)d_in[0];
  const float* y = (const float*)d_in[1];
  float* out = (float*)d_out;

  // ws: xb 8MB | yb 8MB | x2 256KB | y2 256KB | HX 256KB | flagsG 256B
  char* ws = (char*)d_ws;
  const size_t XB = (size_t)B_ * L_ * C_ * 2;
  const size_t NB = (size_t)B_ * L_ * 4;
  ushort_t* xb = (ushort_t*)ws;
  ushort_t* yb = (ushort_t*)(ws + XB);
  float* x2 = (float*)(ws + 2 * XB);
  float* y2 = (float*)(ws + 2 * XB + NB);
  float* HX = (float*)(ws + 2 * XB + 2 * NB);
  int* flagsG = (int*)(ws + 2 * XB + 3 * NB);

  prep_kernel<<<512, 256, 0, stream>>>(x, y, xb, yb, x2, y2, flagsG);
  sdtw_kernel<<<128, 512, 0, stream>>>(xb, yb, x2, y2, HX, flagsG, out);
}